// Round 7
// baseline (390.726 us; speedup 1.0000x reference)
//
#include <hip/hip_runtime.h>

#define NN 4096
#define NE 65536
#define ND 64

// ---------- workspace layout (bytes) ----------
// 0      : srel   f64[NN]   (32768)
// 32768  : sroot  f64[NN]   (32768)
// 65536  : map    i32[NN]
// 81920  : rem    i32[NN]
// 98304  : relab  i32[NN]
// 114688 : perma  i32[NN]   (K5 writes rank2node here; K34 stages it to LDS,
//                            then overwrites with perm output — barrier-separated)
// 131072 : nkeep  i32
// 131136 : cnt    i32[NN]   (K1)  -> rl (len|self<<16) i32[NN] (K5+)
// 147520 : rowst  i32[NN+1] (pad to 16448)
// 163968 : cursor i32[NN]   (K3)  -> key u32[NN] (K4+)
// 180352 : incsr  u16[NE]   (128K; K3 scatter, K5 sorts in place)

// ---------------- K1: per-node dots + in-degree count (multi-CU) ----------------
// NOTE (r5 lesson): no done-counter+__threadfence fusion — device fence from 1024
// blocks forced ~2.1MB L2 writebacks, +60us.
__global__ void k1_dots_count(const float* __restrict__ x, const float* __restrict__ wrel,
                              const float* __restrict__ wroot, const int* __restrict__ ei,
                              double* __restrict__ srel, double* __restrict__ sroot,
                              int* __restrict__ cnt) {
    int gt = blockIdx.x * blockDim.x + threadIdx.x;
    int node = gt >> 6, lane = gt & 63;
    double xv = (double)x[gt];
    double pr = xv * (double)wrel[lane];
    double po = xv * (double)wroot[lane];
    for (int off = 32; off > 0; off >>= 1) {
        pr += __shfl_down(pr, off);
        po += __shfl_down(po, off);
    }
    if (lane == 0) {
        srel[node] = pr;
        sroot[node] = po;
    }
    if (gt < NE / 4) {                                   // extra role: degree count
        const int4* eid4 = (const int4*)(ei + NE);
        int4 q = eid4[gt];
        atomicAdd(&cnt[q.x], 1);
        atomicAdd(&cnt[q.y], 1);
        atomicAdd(&cnt[q.z], 1);
        atomicAdd(&cnt[q.w], 1);
    }
}

// ---------------- K2: exclusive prefix scan of degrees (1 block) ----------------
__global__ void __launch_bounds__(1024) k2_scan(const int* __restrict__ cnt,
                                                int* __restrict__ rowst,
                                                int* __restrict__ cursor) {
    __shared__ int wt[16];
    int tid = threadIdx.x, lane = tid & 63, wv = tid >> 6;
    int4 c = ((const int4*)cnt)[tid];
    int tot = c.x + c.y + c.z + c.w;
    int inc = tot;
    for (int off = 1; off < 64; off <<= 1) {
        int v = __shfl_up(inc, off);
        if (lane >= off) inc += v;
    }
    if (lane == 63) wt[wv] = inc;
    __syncthreads();
    if (wv == 0 && lane < 16) {
        int v = wt[lane];
        for (int off = 1; off < 16; off <<= 1) {
            int u2 = __shfl_up(v, off);
            if (lane >= off) v += u2;
        }
        wt[lane] = v;
    }
    __syncthreads();
    int waveoff = (wv > 0) ? wt[wv - 1] : 0;
    int excl = waveoff + inc - tot;
    int4 rs;
    rs.x = excl; rs.y = excl + c.x; rs.z = excl + c.x + c.y; rs.w = excl + c.x + c.y + c.z;
    ((int4*)rowst)[tid] = rs;
    ((int4*)cursor)[tid] = rs;
    if (tid == 0) rowst[NN] = NE;
}

// ---------------- K3: scatter in-edges (row = dst, entry = src) ----------------
__global__ void k3_scatter(const int* __restrict__ ei, int* __restrict__ cursor,
                           unsigned short* __restrict__ incsr) {
    int i = blockIdx.x * blockDim.x + threadIdx.x;     // i < NE/4
    const int4* eis4 = (const int4*)ei;
    const int4* eid4 = (const int4*)(ei + NE);
    int4 s = eis4[i];
    int4 d = eid4[i];
    incsr[atomicAdd(&cursor[d.x], 1)] = (unsigned short)s.x;
    incsr[atomicAdd(&cursor[d.y], 1)] = (unsigned short)s.y;
    incsr[atomicAdd(&cursor[d.z], 1)] = (unsigned short)s.z;
    incsr[atomicAdd(&cursor[d.w], 1)] = (unsigned short)s.w;
}

// ---------------- K4: per-node agg + monotone key (multi-CU) ----------------
__global__ void k4_keys(const double* __restrict__ srel, const double* __restrict__ sroot,
                        const float* __restrict__ bptr, const int* __restrict__ rowst,
                        const unsigned short* __restrict__ incsr, unsigned* __restrict__ key) {
    int v = blockIdx.x * blockDim.x + threadIdx.x;     // v < NN
    int rs = rowst[v], re = rowst[v + 1];
    double s = 0.0;
    for (int e = rs; e < re; ++e) s += srel[(int)incsr[e]];
    double arg = s + sroot[v] + (double)bptr[0];
    float sc = tanhf((float)arg);                      // f32 saturation => ref ties
    unsigned m = __float_as_uint(sc);
    m = (m & 0x80000000u) ? ~m : (m | 0x80000000u);    // monotone ascending in score
    key[v] = m;
}

// ------- K5: per-row filter + 64-lane bitonic sort; side jobs: out-zero + rank -------
// Rank job (blocks 0..15): rank[v] = #{u : earlier(u,v)}; earlier(u,v) <=>
// key_u>key_v || (key_u==key_v && u<v). Writes rank2node[rank]=v. LDS-broadcast
// count-compare: 4096 iters/thread, uniform address across lanes => conflict-free.
__global__ void k5_filtersort(const int* __restrict__ rowst, const unsigned* __restrict__ key,
                              unsigned short* __restrict__ incsr, int* __restrict__ rl,
                              int* __restrict__ r2n, float* __restrict__ out) {
    // side job A: zero x_pooled region of out (replaces a memset dispatch)
    int g = blockIdx.x * blockDim.x + threadIdx.x;
    if (g < (NN * ND) / 4) ((float4*)out)[g] = make_float4(0.f, 0.f, 0.f, 0.f);

    int v = g >> 6, l = g & 63;
    int rs = rowst[v], deg = rowst[v + 1] - rs;
    unsigned mv = key[v];
    if (deg <= 64) {
        int u = (l < deg) ? (int)incsr[rs + l] : -1;
        bool isself = (l < deg) && (u == v);
        unsigned mu = (l < deg && !isself) ? key[u] : 0u;
        bool keep = (l < deg) && !isself && (mu > mv || (mu == mv && u < v));
        unsigned long long val = keep
            ? ((((unsigned long long)(~mu)) << 12) | (unsigned)u) : ~0ULL;
        int m = __popcll(__ballot(keep));
        bool selfAny = __ballot(isself) != 0ULL;
        for (int k = 2; k <= 64; k <<= 1) {
            for (int j = k >> 1; j > 0; j >>= 1) {
                unsigned long long o = __shfl_xor(val, j);
                bool takeMin = ((l & k) == 0) == ((l & j) == 0);
                unsigned long long mn = (o < val) ? o : val;
                unsigned long long mx = (o < val) ? val : o;
                val = takeMin ? mn : mx;
            }
        }
        if (l < m) incsr[rs + l] = (unsigned short)(val & 0xFFFULL);
        if (l == 0) rl[v] = m | (selfAny ? 0x10000 : 0);
    } else if (l == 0) {
        // fallback (not expected for this input): sequential filter + insertion
        int w = rs;
        bool selfAny = false;
        for (int e = rs; e < rs + deg; ++e) {
            int u = (int)incsr[e];
            if (u == v) { selfAny = true; continue; }
            unsigned mu = key[u];
            if (!(mu > mv || (mu == mv && u < v))) continue;
            int j = w;
            while (j > rs) {
                int q = (int)incsr[j - 1];
                unsigned mq = key[q];
                if (mu > mq || (mu == mq && u < q)) { incsr[j] = (unsigned short)q; --j; }
                else break;
            }
            incsr[j] = (unsigned short)u; ++w;
        }
        rl[v] = (w - rs) | (selfAny ? 0x10000 : 0);
    }

    // side job B: global rank by count-compare (blocks 0..15 only)
    __shared__ unsigned kk[NN];        // 16KB
    if (blockIdx.x < 16) {
        for (int i = threadIdx.x; i < NN; i += 256) kk[i] = key[i];
        __syncthreads();
        int vv = (blockIdx.x << 8) | threadIdx.x;
        unsigned kv = kk[vv];
        int rank = 0;
        for (int u4 = 0; u4 < NN; u4 += 4) {
            unsigned a = kk[u4], b = kk[u4 + 1], c = kk[u4 + 2], d = kk[u4 + 3];
            rank += (a > kv || (a == kv && (u4    ) < vv));
            rank += (b > kv || (b == kv && (u4 + 1) < vv));
            rank += (c > kv || (c == kv && (u4 + 2) < vv));
            rank += (d > kv || (d == kv && (u4 + 3) < vv));
        }
        r2n[rank] = vv;
    }
}

// ---------- K34: 1-CU rank-scheduled chunk contraction (deterministic) ----------
// One wave walks 64 chunks of 64 rank-consecutive nodes. All dependencies point
// to smaller ranks: chunks <c fully resolved; in-chunk deps point to lower lanes
// and settle in <=64 ballot rounds (>=1 lane decided/round; typically ~2).
// Semantics identical to verified front-chase: absorber = first CENTER in the
// key-sorted row; absorbed entries skipped; exhausted row => center.
__global__ void __launch_bounds__(1024) k34_fix(
        const int* __restrict__ rowst, const int* __restrict__ rl,
        const unsigned short* __restrict__ incsr_g, const int* __restrict__ r2n_g,
        int* __restrict__ map_g, int* __restrict__ rem_g, int* __restrict__ relab_g,
        int* __restrict__ perm_a, int* __restrict__ nkeep_g) {
    __shared__ __align__(16) char buf[155712];
    unsigned short* incsr = (unsigned short*)buf;                        // 128K
    unsigned short* r2n   = (unsigned short*)(buf + 131072);             // 8K
    unsigned short* rst   = (unsigned short*)(buf + 139264);             // 8K (u16 ok:
                                                                         //  start<=65535 when len>=1)
    unsigned char*  lsf   = (unsigned char*)(buf + 147456);              // 4K len|self<<7
    volatile unsigned char* stat = (volatile unsigned char*)(buf + 151552); // 4K
    int* wt = (int*)(buf + 155648);
    int tid = threadIdx.x, lane = tid & 63, wv = tid >> 6;

    for (int i = tid; i < 8192; i += 1024)
        ((int4*)incsr)[i] = ((const int4*)incsr_g)[i];
    #pragma unroll
    for (int t = 0; t < 4; ++t) {
        int v = (tid << 2) | t;
        r2n[v] = (unsigned short)r2n_g[v];
        rst[v] = (unsigned short)rowst[v];
        int q = rl[v];
        lsf[v] = (unsigned char)((q & 0x7F) | ((q & 0x10000) ? 0x80 : 0));
        stat[v] = 0;
    }
    __syncthreads();

    if (wv == 0) {
        for (int c = 0; c < 64; ++c) {
            int v = (int)r2n[(c << 6) | lane];
            int len = lsf[v] & 0x7F;
            int lo = (int)rst[v];
            int p = 0;
            bool undec = (len != 0);
            if (!undec) { map_g[v] = v; stat[v] = 1; }   // empty row: center
            int rounds = 0;
            while (__ballot(undec) != 0ULL && rounds < 200) {
                ++rounds;
                if (undec) {
                    while (p < len) {
                        int u = (int)incsr[lo + p];
                        int st = (int)stat[u];
                        if (st == 2) { ++p; continue; }          // absorbed: skip
                        if (st == 1) {                           // first center: absorber
                            map_g[v] = u; stat[v] = 2; undec = false;
                        }
                        break;                                   // st==0: in-chunk, wait
                    }
                    if (undec && p >= len) {                     // exhausted: center
                        map_g[v] = v; stat[v] = 1; undec = false;
                    }
                }
            }
        }
    }
    __syncthreads();

    // relabel prefix + perm + globals
    int remb[4], cnt4 = 0;
    #pragma unroll
    for (int t = 0; t < 4; ++t) {
        int v = (tid << 2) | t;
        remb[t] = (stat[v] == 1) && !(lsf[v] & 0x80);
        cnt4 += remb[t];
    }
    int inc2 = cnt4;
    for (int off = 1; off < 64; off <<= 1) {
        int v = __shfl_up(inc2, off);
        if (lane >= off) inc2 += v;
    }
    if (lane == 63) wt[wv] = inc2;
    __syncthreads();
    if (wv == 0 && lane < 16) {
        int v = wt[lane];
        for (int off = 1; off < 16; off <<= 1) {
            int u2 = __shfl_up(v, off);
            if (lane >= off) v += u2;
        }
        wt[lane] = v;
    }
    __syncthreads();
    int woff2 = (wv > 0) ? wt[wv - 1] : 0;
    int run = woff2 + inc2 - cnt4;
    #pragma unroll
    for (int t = 0; t < 4; ++t) {
        int v = (tid << 2) | t;
        relab_g[v] = run;
        if (remb[t]) { perm_a[run] = v; ++run; }
        rem_g[v] = remb[t];
    }
    if (tid == 1023) nkeep_g[0] = run;
}

// ---------------- K56: all outputs; x region is pure atomic-add over zeroed base ----
__global__ void k56_outputs(const float* __restrict__ x, const int* __restrict__ map_g,
                            const int* __restrict__ rem_g, const int* __restrict__ relab_g,
                            const int* __restrict__ perm_a, const int* __restrict__ ei,
                            const int* __restrict__ batch, const int* __restrict__ nkeep_g,
                            float* __restrict__ out) {
    int idx = blockIdx.x * blockDim.x + threadIdx.x;
    if (idx < NN * ND) {
        int n = idx >> 6, d = idx & 63;
        int m = map_g[n];                 // m==n for centers & kept free nodes
        if (rem_g[m]) atomicAdd(&out[relab_g[m] * ND + d], x[idx]);
    } else if (idx < NN * ND + 2 * NE) {
        int e = idx - NN * ND;
        int row = e >> 16;                // NE == 1<<16
        int ee = e & (NE - 1);
        int s = ei[ee], t = ei[NE + ee];
        bool valid = (rem_g[s] != 0) && (rem_g[t] != 0);
        int endp = (row == 0) ? s : t;
        out[idx] = valid ? (float)relab_g[endp] : -1.0f;
    } else if (idx < NN * ND + 2 * NE + NN) {
        int r = idx - (NN * ND + 2 * NE);
        int nk = nkeep_g[0];
        out[idx] = (r < nk) ? (float)batch[perm_a[r]] : -1.0f;
    } else if (idx < NN * ND + 2 * NE + 2 * NN) {
        int r = idx - (NN * ND + 2 * NE + NN);
        int nk = nkeep_g[0];
        out[idx] = (r < nk) ? (float)perm_a[r] : -1.0f;
    }
}

extern "C" void kernel_launch(void* const* d_in, const int* in_sizes, int n_in,
                              void* d_out, int out_size, void* d_ws, size_t ws_size,
                              hipStream_t stream) {
    const float* x     = (const float*)d_in[0];
    const int*   ei    = (const int*)d_in[1];
    const int*   batch = (const int*)d_in[2];
    const float* wrel  = (const float*)d_in[3];
    const float* wroot = (const float*)d_in[4];
    const float* b     = (const float*)d_in[5];

    char* ws = (char*)d_ws;
    double* srel   = (double*)(ws + 0);
    double* sroot  = (double*)(ws + 32768);
    int*    map_g  = (int*)(ws + 65536);
    int*    rem_g  = (int*)(ws + 81920);
    int*    relab  = (int*)(ws + 98304);
    int*    perma  = (int*)(ws + 114688);    // rank2node (K5) then perm (K34)
    int*    nkeep  = (int*)(ws + 131072);
    int*    cnt    = (int*)(ws + 131136);    // -> rl after K5
    int*    rowst  = (int*)(ws + 147520);
    int*    cursor = (int*)(ws + 163968);    // -> key after K4
    unsigned short* incsr = (unsigned short*)(ws + 180352);
    int*      rl  = cnt;
    unsigned* key = (unsigned*)cursor;

    float* out = (float*)d_out;

    hipMemsetAsync(cnt, 0, NN * sizeof(int), stream);
    k1_dots_count<<<NN * ND / 256, 256, 0, stream>>>(x, wrel, wroot, ei, srel, sroot, cnt);
    k2_scan<<<1, 1024, 0, stream>>>(cnt, rowst, cursor);
    k3_scatter<<<(NE / 4) / 256, 256, 0, stream>>>(ei, cursor, incsr);
    k4_keys<<<NN / 256, 256, 0, stream>>>(srel, sroot, b, rowst, incsr, key);
    k5_filtersort<<<(NN * 64) / 256, 256, 0, stream>>>(rowst, key, incsr, rl, perma, out);
    k34_fix<<<1, 1024, 0, stream>>>(rowst, rl, incsr, perma, map_g, rem_g, relab,
                                    perma, nkeep);
    int total_out = NN * ND + 2 * NE + 2 * NN;  // 401408
    k56_outputs<<<(total_out + 255) / 256, 256, 0, stream>>>(x, map_g, rem_g, relab,
                                                             perma, ei, batch, nkeep, out);
}

// Round 8
// 302.176 us; speedup vs baseline: 1.2930x; 1.2930x over previous
//
#include <hip/hip_runtime.h>

#define NN 4096
#define NE 65536
#define ND 64

// ---------- workspace layout (bytes) ----------
// 0      : srel   f64[NN]   (32768)
// 32768  : sroot  f64[NN]   (32768)
// 65536  : map    i32[NN]
// 81920  : rem    i32[NN]
// 98304  : relab  i32[NN]
// 114688 : perma  i32[NN]   (K5 writes rank2node; K34 stages it, then overwrites
//                            with perm output — barrier-separated)
// 131072 : nkeep  i32
// 131136 : cnt    i32[NN]   (K1)  -> rl (len|self<<16) i32[NN] (K5+)
// 147520 : rowst  i32[NN+1]
// 163968 : cursor i32[NN]   (K3)  -> key u32[NN] (K4+)
// 180352 : incsr  u16[NE]   (128K; K3 scatter, K5 sorts in place)

// ---------------- K1: per-node dots + in-degree count (multi-CU) ----------------
// r5 lesson: no done-counter+__threadfence fusion (device fences from 1024 blocks
// forced ~2.1MB L2 writebacks, +60us).
__global__ void k1_dots_count(const float* __restrict__ x, const float* __restrict__ wrel,
                              const float* __restrict__ wroot, const int* __restrict__ ei,
                              double* __restrict__ srel, double* __restrict__ sroot,
                              int* __restrict__ cnt) {
    int gt = blockIdx.x * blockDim.x + threadIdx.x;
    int node = gt >> 6, lane = gt & 63;
    double xv = (double)x[gt];
    double pr = xv * (double)wrel[lane];
    double po = xv * (double)wroot[lane];
    for (int off = 32; off > 0; off >>= 1) {
        pr += __shfl_down(pr, off);
        po += __shfl_down(po, off);
    }
    if (lane == 0) {
        srel[node] = pr;
        sroot[node] = po;
    }
    if (gt < NE / 4) {
        const int4* eid4 = (const int4*)(ei + NE);
        int4 q = eid4[gt];
        atomicAdd(&cnt[q.x], 1);
        atomicAdd(&cnt[q.y], 1);
        atomicAdd(&cnt[q.z], 1);
        atomicAdd(&cnt[q.w], 1);
    }
}

// ---------------- K2: exclusive prefix scan of degrees (1 block) ----------------
__global__ void __launch_bounds__(1024) k2_scan(const int* __restrict__ cnt,
                                                int* __restrict__ rowst,
                                                int* __restrict__ cursor) {
    __shared__ int wt[16];
    int tid = threadIdx.x, lane = tid & 63, wv = tid >> 6;
    int4 c = ((const int4*)cnt)[tid];
    int tot = c.x + c.y + c.z + c.w;
    int inc = tot;
    for (int off = 1; off < 64; off <<= 1) {
        int v = __shfl_up(inc, off);
        if (lane >= off) inc += v;
    }
    if (lane == 63) wt[wv] = inc;
    __syncthreads();
    if (wv == 0 && lane < 16) {
        int v = wt[lane];
        for (int off = 1; off < 16; off <<= 1) {
            int u2 = __shfl_up(v, off);
            if (lane >= off) v += u2;
        }
        wt[lane] = v;
    }
    __syncthreads();
    int waveoff = (wv > 0) ? wt[wv - 1] : 0;
    int excl = waveoff + inc - tot;
    int4 rs;
    rs.x = excl; rs.y = excl + c.x; rs.z = excl + c.x + c.y; rs.w = excl + c.x + c.y + c.z;
    ((int4*)rowst)[tid] = rs;
    ((int4*)cursor)[tid] = rs;
    if (tid == 0) rowst[NN] = NE;
}

// ---------------- K3: scatter in-edges (row = dst, entry = src) ----------------
__global__ void k3_scatter(const int* __restrict__ ei, int* __restrict__ cursor,
                           unsigned short* __restrict__ incsr) {
    int i = blockIdx.x * blockDim.x + threadIdx.x;
    const int4* eis4 = (const int4*)ei;
    const int4* eid4 = (const int4*)(ei + NE);
    int4 s = eis4[i];
    int4 d = eid4[i];
    incsr[atomicAdd(&cursor[d.x], 1)] = (unsigned short)s.x;
    incsr[atomicAdd(&cursor[d.y], 1)] = (unsigned short)s.y;
    incsr[atomicAdd(&cursor[d.z], 1)] = (unsigned short)s.z;
    incsr[atomicAdd(&cursor[d.w], 1)] = (unsigned short)s.w;
}

// ---------------- K4: per-node agg + monotone key (multi-CU) ----------------
__global__ void k4_keys(const double* __restrict__ srel, const double* __restrict__ sroot,
                        const float* __restrict__ bptr, const int* __restrict__ rowst,
                        const unsigned short* __restrict__ incsr, unsigned* __restrict__ key) {
    int v = blockIdx.x * blockDim.x + threadIdx.x;
    int rs = rowst[v], re = rowst[v + 1];
    double s = 0.0;
    for (int e = rs; e < re; ++e) s += srel[(int)incsr[e]];
    double arg = s + sroot[v] + (double)bptr[0];
    float sc = tanhf((float)arg);                      // f32 saturation => ref ties
    unsigned m = __float_as_uint(sc);
    m = (m & 0x80000000u) ? ~m : (m | 0x80000000u);    // monotone ascending in score
    key[v] = m;
}

// ------- K5: per-row filter + 64-lane bitonic sort; side jobs: out-zero + rank -------
__global__ void k5_filtersort(const int* __restrict__ rowst, const unsigned* __restrict__ key,
                              unsigned short* __restrict__ incsr, int* __restrict__ rl,
                              int* __restrict__ r2n, float* __restrict__ out) {
    // side job A: zero x_pooled region of out (replaces a memset dispatch)
    int g = blockIdx.x * blockDim.x + threadIdx.x;
    if (g < (NN * ND) / 4) ((float4*)out)[g] = make_float4(0.f, 0.f, 0.f, 0.f);

    int v = g >> 6, l = g & 63;
    int rs = rowst[v], deg = rowst[v + 1] - rs;
    unsigned mv = key[v];
    if (deg <= 64) {
        int u = (l < deg) ? (int)incsr[rs + l] : -1;
        bool isself = (l < deg) && (u == v);
        unsigned mu = (l < deg && !isself) ? key[u] : 0u;
        bool keep = (l < deg) && !isself && (mu > mv || (mu == mv && u < v));
        unsigned long long val = keep
            ? ((((unsigned long long)(~mu)) << 12) | (unsigned)u) : ~0ULL;
        int m = __popcll(__ballot(keep));
        bool selfAny = __ballot(isself) != 0ULL;
        for (int k = 2; k <= 64; k <<= 1) {
            for (int j = k >> 1; j > 0; j >>= 1) {
                unsigned long long o = __shfl_xor(val, j);
                bool takeMin = ((l & k) == 0) == ((l & j) == 0);
                unsigned long long mn = (o < val) ? o : val;
                unsigned long long mx = (o < val) ? val : o;
                val = takeMin ? mn : mx;
            }
        }
        if (l < m) incsr[rs + l] = (unsigned short)(val & 0xFFFULL);
        if (l == 0) rl[v] = m | (selfAny ? 0x10000 : 0);
    } else if (l == 0) {
        int w = rs;
        bool selfAny = false;
        for (int e = rs; e < rs + deg; ++e) {
            int u = (int)incsr[e];
            if (u == v) { selfAny = true; continue; }
            unsigned mu = key[u];
            if (!(mu > mv || (mu == mv && u < v))) continue;
            int j = w;
            while (j > rs) {
                int q = (int)incsr[j - 1];
                unsigned mq = key[q];
                if (mu > mq || (mu == mq && u < q)) { incsr[j] = (unsigned short)q; --j; }
                else break;
            }
            incsr[j] = (unsigned short)u; ++w;
        }
        rl[v] = (w - rs) | (selfAny ? 0x10000 : 0);
    }

    // side job B: global rank by count-compare (blocks 0..15 only)
    __shared__ unsigned kk[NN];        // 16KB
    if (blockIdx.x < 16) {
        for (int i = threadIdx.x; i < NN; i += 256) kk[i] = key[i];
        __syncthreads();
        int vv = (blockIdx.x << 8) | threadIdx.x;
        unsigned kv = kk[vv];
        int rank = 0;
        for (int u4 = 0; u4 < NN; u4 += 4) {
            unsigned a = kk[u4], b = kk[u4 + 1], c = kk[u4 + 2], d = kk[u4 + 3];
            rank += (a > kv || (a == kv && (u4    ) < vv));
            rank += (b > kv || (b == kv && (u4 + 1) < vv));
            rank += (c > kv || (c == kv && (u4 + 2) < vv));
            rank += (d > kv || (d == kv && (u4 + 3) < vv));
        }
        r2n[rank] = vv;
    }
}

// ---- K34: rank-scheduled chunk contraction, FULL-BLOCK per chunk (r7 fix) ----
// 64 chunks of 64 rank-consecutive nodes. Per chunk: (a) 1024-thread pre-scan,
// 16 threads/row, batched LDS reads -> m1 (first resolved-center pos) + pend
// (bitmask of in-chunk dep lanes before m1); (b) wave-0 register/ballot fixpoint
// (deps point to lower lanes; >=1 lane resolves per round). In-chunk membership
// is encoded in stat: 0x80|lane (entries have strictly smaller rank => entry is
// resolved (1/2) or in current chunk; stat==0 unreachable during pre-scan).
// Semantics == verified front-chase: first non-absorbed entry in key order
// decides; exhausted => center.
__global__ void __launch_bounds__(1024) k34_fix(
        const int* __restrict__ rowst, const int* __restrict__ rl,
        const unsigned short* __restrict__ incsr_g, const int* __restrict__ r2n_g,
        int* __restrict__ map_g, int* __restrict__ rem_g, int* __restrict__ relab_g,
        int* __restrict__ perm_a, int* __restrict__ nkeep_g) {
    __shared__ __align__(16) char buf[156480];
    unsigned short* incsr = (unsigned short*)buf;                      // 128K
    unsigned short* r2n   = (unsigned short*)(buf + 131072);           // 8K
    unsigned short* rst   = (unsigned short*)(buf + 139264);           // 8K (start<=65535 when len>=1)
    unsigned char*  lenb  = (unsigned char*)(buf + 147456);            // 4K len|self<<7
    unsigned char*  stat  = (unsigned char*)(buf + 151552);            // 4K
    unsigned long long* pendL = (unsigned long long*)(buf + 155648);   // 512
    int* m1L = (int*)(buf + 156160);                                   // 256
    int* wt  = (int*)(buf + 156416);                                   // 64
    int tid = threadIdx.x, lane = tid & 63, wv = tid >> 6;
    const int INF = 0x7FFFFFFF;

    // ---- stage ----
    for (int i = tid; i < 8192; i += 1024)
        ((int4*)incsr)[i] = ((const int4*)incsr_g)[i];
    #pragma unroll
    for (int t = 0; t < 4; ++t) {
        int v = (tid << 2) | t;
        r2n[v] = (unsigned short)r2n_g[v];
        rst[v] = (unsigned short)rowst[v];
        int q = rl[v];
        lenb[v] = (unsigned char)((q & 0x7F) | ((q & 0x10000) ? 0x80 : 0));
        stat[v] = 0;
    }
    __syncthreads();
    if (tid < 64) stat[r2n[tid]] = (unsigned char)(0x80 | tid);   // mark chunk 0
    __syncthreads();

    // ---- 64 chunk steps ----
    for (int c = 0; c < 64; ++c) {
        int row = tid >> 4, s = tid & 15;
        int v = (int)r2n[(c << 6) | row];
        int lo = (int)rst[v];
        int L = lenb[v] & 0x7F;
        // batched entry reads (positions s, s+16, s+32, s+48)
        int uu[4]; int st[4];
        #pragma unroll
        for (int i = 0; i < 4; ++i) {
            int p = s + (i << 4);
            uu[i] = (p < L) ? (int)incsr[lo + p] : -1;
        }
        #pragma unroll
        for (int i = 0; i < 4; ++i)
            st[i] = (uu[i] >= 0) ? (int)stat[uu[i]] : -1;
        // m1: min packed (pos<<12|node) over entries with st==1
        int m1 = INF;
        #pragma unroll
        for (int i = 0; i < 4; ++i) {
            int p = s + (i << 4);
            if (st[i] == 1) { int pk = (p << 12) | uu[i]; m1 = (pk < m1) ? pk : m1; }
        }
        #pragma unroll
        for (int j = 1; j < 16; j <<= 1) {
            int o = __shfl_xor(m1, j);
            m1 = (o < m1) ? o : m1;
        }
        int m1pos = m1 >> 12;
        // pend: dep lanes (st>=0x80) with pos < m1pos
        unsigned long long pend = 0ULL;
        #pragma unroll
        for (int i = 0; i < 4; ++i) {
            int p = s + (i << 4);
            if (st[i] >= 0x80 && p < m1pos) pend |= 1ULL << (st[i] & 63);
        }
        #pragma unroll
        for (int j = 1; j < 16; j <<= 1) pend |= __shfl_xor(pend, j);
        if (s == 0) { pendL[row] = pend; m1L[row] = m1; }
        __syncthreads();

        if (wv == 0) {
            unsigned long long pd = pendL[lane];
            int m1v = m1L[lane];
            int vv = (int)r2n[(c << 6) | lane];
            unsigned long long C = 0ULL, A = 0ULL;
            bool res = false, isC = false;
            int ab = vv;
            for (int r = 0; r < 70; ++r) {
                if (!res) {
                    unsigned long long live = pd & ~A;
                    if (live == 0ULL) {
                        res = true;
                        if (m1v == INF) { isC = true; ab = vv; }
                        else { isC = false; ab = m1v & 0xFFF; }
                    } else {
                        int f = __ffsll((long long)live) - 1;
                        if ((C >> f) & 1ULL) {
                            res = true; isC = false; ab = (int)r2n[(c << 6) | f];
                        }
                    }
                }
                C = __ballot(res && isC);
                A = __ballot(res && !isC);
                if (__ballot(!res) == 0ULL) break;
            }
            stat[vv] = isC ? 1 : 2;
            map_g[vv] = ab;
            if (c < 63) stat[r2n[((c + 1) << 6) | lane]] = (unsigned char)(0x80 | lane);
        }
        __syncthreads();
    }

    // ---- relabel prefix + perm + globals ----
    int remb[4], cnt4 = 0;
    #pragma unroll
    for (int t = 0; t < 4; ++t) {
        int v = (tid << 2) | t;
        remb[t] = (stat[v] == 1) && !(lenb[v] & 0x80);
        cnt4 += remb[t];
    }
    int inc2 = cnt4;
    for (int off = 1; off < 64; off <<= 1) {
        int v = __shfl_up(inc2, off);
        if (lane >= off) inc2 += v;
    }
    if (lane == 63) wt[wv] = inc2;
    __syncthreads();
    if (wv == 0 && lane < 16) {
        int v = wt[lane];
        for (int off = 1; off < 16; off <<= 1) {
            int u2 = __shfl_up(v, off);
            if (lane >= off) v += u2;
        }
        wt[lane] = v;
    }
    __syncthreads();
    int woff2 = (wv > 0) ? wt[wv - 1] : 0;
    int run = woff2 + inc2 - cnt4;
    #pragma unroll
    for (int t = 0; t < 4; ++t) {
        int v = (tid << 2) | t;
        relab_g[v] = run;
        if (remb[t]) { perm_a[run] = v; ++run; }
        rem_g[v] = remb[t];
    }
    if (tid == 1023) nkeep_g[0] = run;
}

// ---------------- K56: all outputs; x region is pure atomic-add over zeroed base ----
__global__ void k56_outputs(const float* __restrict__ x, const int* __restrict__ map_g,
                            const int* __restrict__ rem_g, const int* __restrict__ relab_g,
                            const int* __restrict__ perm_a, const int* __restrict__ ei,
                            const int* __restrict__ batch, const int* __restrict__ nkeep_g,
                            float* __restrict__ out) {
    int idx = blockIdx.x * blockDim.x + threadIdx.x;
    if (idx < NN * ND) {
        int n = idx >> 6, d = idx & 63;
        int m = map_g[n];
        if (rem_g[m]) atomicAdd(&out[relab_g[m] * ND + d], x[idx]);
    } else if (idx < NN * ND + 2 * NE) {
        int e = idx - NN * ND;
        int row = e >> 16;
        int ee = e & (NE - 1);
        int s = ei[ee], t = ei[NE + ee];
        bool valid = (rem_g[s] != 0) && (rem_g[t] != 0);
        int endp = (row == 0) ? s : t;
        out[idx] = valid ? (float)relab_g[endp] : -1.0f;
    } else if (idx < NN * ND + 2 * NE + NN) {
        int r = idx - (NN * ND + 2 * NE);
        int nk = nkeep_g[0];
        out[idx] = (r < nk) ? (float)batch[perm_a[r]] : -1.0f;
    } else if (idx < NN * ND + 2 * NE + 2 * NN) {
        int r = idx - (NN * ND + 2 * NE + NN);
        int nk = nkeep_g[0];
        out[idx] = (r < nk) ? (float)perm_a[r] : -1.0f;
    }
}

extern "C" void kernel_launch(void* const* d_in, const int* in_sizes, int n_in,
                              void* d_out, int out_size, void* d_ws, size_t ws_size,
                              hipStream_t stream) {
    const float* x     = (const float*)d_in[0];
    const int*   ei    = (const int*)d_in[1];
    const int*   batch = (const int*)d_in[2];
    const float* wrel  = (const float*)d_in[3];
    const float* wroot = (const float*)d_in[4];
    const float* b     = (const float*)d_in[5];

    char* ws = (char*)d_ws;
    double* srel   = (double*)(ws + 0);
    double* sroot  = (double*)(ws + 32768);
    int*    map_g  = (int*)(ws + 65536);
    int*    rem_g  = (int*)(ws + 81920);
    int*    relab  = (int*)(ws + 98304);
    int*    perma  = (int*)(ws + 114688);    // rank2node (K5) then perm (K34)
    int*    nkeep  = (int*)(ws + 131072);
    int*    cnt    = (int*)(ws + 131136);    // -> rl after K5
    int*    rowst  = (int*)(ws + 147520);
    int*    cursor = (int*)(ws + 163968);    // -> key after K4
    unsigned short* incsr = (unsigned short*)(ws + 180352);
    int*      rl  = cnt;
    unsigned* key = (unsigned*)cursor;

    float* out = (float*)d_out;

    hipMemsetAsync(cnt, 0, NN * sizeof(int), stream);
    k1_dots_count<<<NN * ND / 256, 256, 0, stream>>>(x, wrel, wroot, ei, srel, sroot, cnt);
    k2_scan<<<1, 1024, 0, stream>>>(cnt, rowst, cursor);
    k3_scatter<<<(NE / 4) / 256, 256, 0, stream>>>(ei, cursor, incsr);
    k4_keys<<<NN / 256, 256, 0, stream>>>(srel, sroot, b, rowst, incsr, key);
    k5_filtersort<<<(NN * 64) / 256, 256, 0, stream>>>(rowst, key, incsr, rl, perma, out);
    k34_fix<<<1, 1024, 0, stream>>>(rowst, rl, incsr, perma, map_g, rem_g, relab,
                                    perma, nkeep);
    int total_out = NN * ND + 2 * NE + 2 * NN;  // 401408
    k56_outputs<<<(total_out + 255) / 256, 256, 0, stream>>>(x, map_g, rem_g, relab,
                                                             perma, ei, batch, nkeep, out);
}

// Round 9
// 226.590 us; speedup vs baseline: 1.7244x; 1.3336x over previous
//
#include <hip/hip_runtime.h>

#define NN 4096
#define NE 65536
#define ND 64

// ---------- workspace layout (bytes) ----------
// 0      : srel   f64[NN]
// 32768  : sroot  f64[NN]
// 65536  : map    i32[NN]
// 81920  : rem    i32[NN]
// 98304  : relab  i32[NN]
// 114688 : rank   i32[NN]  (K5 writes; K34 stages to LDS r2n, then overwrites
//                           region with perm output — barrier-separated)
// 131072 : nkeep  i32
// 131136 : cnt    i32[NN]  (K1) -> rl (len|self<<16) i32[NN] (K5+)
// 147520 : rowst  i32[NN+1]
// 163968 : cursor i32[NN]  (K3) -> key u32[NN] (K4+)
// 180352 : incsr  u16[NE]  (128K; K3 scatter, K5 sorts rows in place)

// ---------------- K1: per-node dots + in-degree count (multi-CU) ----------------
// r5 lesson: no done-counter+__threadfence fusion (device fences from 1024 blocks
// forced ~2.1MB L2 writebacks, +60us).
__global__ void k1_dots_count(const float* __restrict__ x, const float* __restrict__ wrel,
                              const float* __restrict__ wroot, const int* __restrict__ ei,
                              double* __restrict__ srel, double* __restrict__ sroot,
                              int* __restrict__ cnt) {
    int gt = blockIdx.x * blockDim.x + threadIdx.x;
    int node = gt >> 6, lane = gt & 63;
    double xv = (double)x[gt];
    double pr = xv * (double)wrel[lane];
    double po = xv * (double)wroot[lane];
    for (int off = 32; off > 0; off >>= 1) {
        pr += __shfl_down(pr, off);
        po += __shfl_down(po, off);
    }
    if (lane == 0) {
        srel[node] = pr;
        sroot[node] = po;
    }
    if (gt < NE / 4) {
        const int4* eid4 = (const int4*)(ei + NE);
        int4 q = eid4[gt];
        atomicAdd(&cnt[q.x], 1);
        atomicAdd(&cnt[q.y], 1);
        atomicAdd(&cnt[q.z], 1);
        atomicAdd(&cnt[q.w], 1);
    }
}

// ---------------- K2: exclusive prefix scan of degrees (1 block) ----------------
__global__ void __launch_bounds__(1024) k2_scan(const int* __restrict__ cnt,
                                                int* __restrict__ rowst,
                                                int* __restrict__ cursor) {
    __shared__ int wt[16];
    int tid = threadIdx.x, lane = tid & 63, wv = tid >> 6;
    int4 c = ((const int4*)cnt)[tid];
    int tot = c.x + c.y + c.z + c.w;
    int inc = tot;
    for (int off = 1; off < 64; off <<= 1) {
        int v = __shfl_up(inc, off);
        if (lane >= off) inc += v;
    }
    if (lane == 63) wt[wv] = inc;
    __syncthreads();
    if (wv == 0 && lane < 16) {
        int v = wt[lane];
        for (int off = 1; off < 16; off <<= 1) {
            int u2 = __shfl_up(v, off);
            if (lane >= off) v += u2;
        }
        wt[lane] = v;
    }
    __syncthreads();
    int waveoff = (wv > 0) ? wt[wv - 1] : 0;
    int excl = waveoff + inc - tot;
    int4 rs;
    rs.x = excl; rs.y = excl + c.x; rs.z = excl + c.x + c.y; rs.w = excl + c.x + c.y + c.z;
    ((int4*)rowst)[tid] = rs;
    ((int4*)cursor)[tid] = rs;
    if (tid == 0) rowst[NN] = NE;
}

// ---------------- K3: scatter in-edges (row = dst, entry = src) ----------------
__global__ void k3_scatter(const int* __restrict__ ei, int* __restrict__ cursor,
                           unsigned short* __restrict__ incsr) {
    int i = blockIdx.x * blockDim.x + threadIdx.x;
    const int4* eis4 = (const int4*)ei;
    const int4* eid4 = (const int4*)(ei + NE);
    int4 s = eis4[i];
    int4 d = eid4[i];
    incsr[atomicAdd(&cursor[d.x], 1)] = (unsigned short)s.x;
    incsr[atomicAdd(&cursor[d.y], 1)] = (unsigned short)s.y;
    incsr[atomicAdd(&cursor[d.z], 1)] = (unsigned short)s.z;
    incsr[atomicAdd(&cursor[d.w], 1)] = (unsigned short)s.w;
}

// ---------------- K4: per-node agg + monotone key (multi-CU) ----------------
__global__ void k4_keys(const double* __restrict__ srel, const double* __restrict__ sroot,
                        const float* __restrict__ bptr, const int* __restrict__ rowst,
                        const unsigned short* __restrict__ incsr, unsigned* __restrict__ key) {
    int v = blockIdx.x * blockDim.x + threadIdx.x;
    int rs = rowst[v], re = rowst[v + 1];
    double s = 0.0;
    for (int e = rs; e < re; ++e) s += srel[(int)incsr[e]];
    double arg = s + sroot[v] + (double)bptr[0];
    float sc = tanhf((float)arg);                      // f32 saturation => ref ties
    unsigned m = __float_as_uint(sc);
    m = (m & 0x80000000u) ? ~m : (m | 0x80000000u);    // monotone ascending in score
    key[v] = m;
}

// ------- K5: per-row filter + 64-lane bitonic sort; side jobs: out-zero + rank -------
// r8 lesson: the rank job on 16 blocks was a 115us serial latency tail. Now the
// wave that owns row v computes rank[v]: each lane count-compares 64 keys via
// 16 uint4 L1-hot loads; shuffle-reduce; one plain store. Fully parallel.
__global__ void k5_filtersort(const int* __restrict__ rowst, const unsigned* __restrict__ key,
                              unsigned short* __restrict__ incsr, int* __restrict__ rl,
                              int* __restrict__ rank_g, float* __restrict__ out) {
    // side job A: zero x_pooled region of out (replaces a memset dispatch)
    int g = blockIdx.x * blockDim.x + threadIdx.x;
    if (g < (NN * ND) / 4) ((float4*)out)[g] = make_float4(0.f, 0.f, 0.f, 0.f);

    int v = g >> 6, l = g & 63;
    int rs = rowst[v], deg = rowst[v + 1] - rs;
    unsigned mv = key[v];
    if (deg <= 64) {
        int u = (l < deg) ? (int)incsr[rs + l] : -1;
        bool isself = (l < deg) && (u == v);
        unsigned mu = (l < deg && !isself) ? key[u] : 0u;
        bool keep = (l < deg) && !isself && (mu > mv || (mu == mv && u < v));
        unsigned long long val = keep
            ? ((((unsigned long long)(~mu)) << 12) | (unsigned)u) : ~0ULL;
        int m = __popcll(__ballot(keep));
        bool selfAny = __ballot(isself) != 0ULL;
        // bitonic ascending => row ends up sorted earliest-first (rank ascending)
        for (int k = 2; k <= 64; k <<= 1) {
            for (int j = k >> 1; j > 0; j >>= 1) {
                unsigned long long o = __shfl_xor(val, j);
                bool takeMin = ((l & k) == 0) == ((l & j) == 0);
                unsigned long long mn = (o < val) ? o : val;
                unsigned long long mx = (o < val) ? val : o;
                val = takeMin ? mn : mx;
            }
        }
        if (l < m) incsr[rs + l] = (unsigned short)(val & 0xFFFULL);
        if (l == 0) rl[v] = m | (selfAny ? 0x10000 : 0);
    } else if (l == 0) {
        int w = rs;
        bool selfAny = false;
        for (int e = rs; e < rs + deg; ++e) {
            int u = (int)incsr[e];
            if (u == v) { selfAny = true; continue; }
            unsigned mu = key[u];
            if (!(mu > mv || (mu == mv && u < v))) continue;
            int j = w;
            while (j > rs) {
                int q = (int)incsr[j - 1];
                unsigned mq = key[q];
                if (mu > mq || (mu == mq && u < q)) { incsr[j] = (unsigned short)q; --j; }
                else break;
            }
            incsr[j] = (unsigned short)u; ++w;
        }
        rl[v] = (w - rs) | (selfAny ? 0x10000 : 0);
    }

    // side job B: rank[v] = #{u : key_u>key_v || (key_u==key_v && u<v)}
    {
        int cntk = 0;
        const uint4* k4p = (const uint4*)key;
        #pragma unroll 4
        for (int i = 0; i < 16; ++i) {
            uint4 kq = k4p[(l << 4) | i];
            int u0 = (l << 6) | (i << 2);
            cntk += (kq.x > mv || (kq.x == mv && (u0    ) < v));
            cntk += (kq.y > mv || (kq.y == mv && (u0 + 1) < v));
            cntk += (kq.z > mv || (kq.z == mv && (u0 + 2) < v));
            cntk += (kq.w > mv || (kq.w == mv && (u0 + 3) < v));
        }
        for (int off = 32; off > 0; off >>= 1) cntk += __shfl_down(cntk, off);
        if (l == 0) rank_g[v] = cntk;
    }
}

// ---- K34: rank-chunk contraction, wave-0 batched-read + register-ballot resolve ----
// 64 chunks of 64 rank-consecutive nodes, all handled by wave 0 (no per-chunk
// barriers; r8's full-block pre-scan paid ~800K shuffle/DS ops + 128 barriers).
// Per chunk, lane = rank offset: read first 16 row entries + their stats as TWO
// batched LDS groups (2 latencies — r7's 186us came from a dependent LDS walk),
// rare phase-B segments for rows >16, then resolve in registers via ballot.
// stat: 0=unreached (impossible for row entries), 1=center, 2=absorbed,
// 0x80|lane = in current chunk. Semantics == verified front-chase.
__global__ void __launch_bounds__(1024) k34_fix(
        const int* __restrict__ rowst, const int* __restrict__ rl,
        const unsigned short* __restrict__ incsr_g, const int* __restrict__ rank_g,
        int* __restrict__ map_g, int* __restrict__ rem_g, int* __restrict__ relab_g,
        int* __restrict__ perm_a, int* __restrict__ nkeep_g) {
    __shared__ __align__(16) char buf[155776];
    unsigned short* incsr = (unsigned short*)buf;              // 128K
    unsigned short* r2n   = (unsigned short*)(buf + 131072);   // 8K
    unsigned short* rst   = (unsigned short*)(buf + 139264);   // 8K
    unsigned char*  lenb  = (unsigned char*)(buf + 147456);    // 4K len|self<<7
    unsigned char*  stat  = (unsigned char*)(buf + 151552);    // 4K
    int* wt = (int*)(buf + 155648);
    int tid = threadIdx.x, lane = tid & 63, wv = tid >> 6;
    const int INF = 0x7FFFFFFF;

    // ---- stage (all 1024 threads) ----
    for (int i = tid; i < 8192; i += 1024)
        ((int4*)incsr)[i] = ((const int4*)incsr_g)[i];
    #pragma unroll
    for (int t = 0; t < 4; ++t) {
        int v = (tid << 2) | t;
        rst[v] = (unsigned short)rowst[v];
        int q = rl[v];
        lenb[v] = (unsigned char)((q & 0x7F) | ((q & 0x10000) ? 0x80 : 0));
        stat[v] = 0;
        r2n[rank_g[v]] = (unsigned short)v;    // rank scatter (rank is a permutation)
    }
    __syncthreads();
    if (tid < 64) stat[r2n[tid]] = (unsigned char)(0x80 | tid);   // mark chunk 0
    __syncthreads();

    if (wv == 0) {
        for (int c = 0; c < 64; ++c) {
            int v = (int)r2n[(c << 6) | lane];
            int lo = (int)rst[v];
            int L = lenb[v] & 0x7F;
            // phase A: first 16 entries, two batched LDS groups
            int e[16], s[16];
            #pragma unroll
            for (int i = 0; i < 16; ++i) e[i] = (i < L) ? (int)incsr[lo + i] : -1;
            #pragma unroll
            for (int i = 0; i < 16; ++i) s[i] = (e[i] >= 0) ? (int)stat[e[i]] : -1;
            unsigned long long pend = 0ULL;
            int m1 = INF;                      // packed (pos<<12)|node of first center
            bool foundC = false;
            #pragma unroll
            for (int i = 0; i < 16; ++i) {
                if (!foundC) {
                    if (s[i] == 1) { m1 = (i << 12) | e[i]; foundC = true; }
                    else if (s[i] >= 0x80) pend |= 1ULL << (s[i] & 63);
                    // s==2 absorbed: skip; s==-1 past end
                }
            }
            // phase B: rare long rows
            int p = 16;
            while (p < L && !foundC) {
                int eb[8], sb[8];
                #pragma unroll
                for (int j = 0; j < 8; ++j)
                    eb[j] = (p + j < L) ? (int)incsr[lo + p + j] : -1;
                #pragma unroll
                for (int j = 0; j < 8; ++j)
                    sb[j] = (eb[j] >= 0) ? (int)stat[eb[j]] : -1;
                #pragma unroll
                for (int j = 0; j < 8; ++j) {
                    if (!foundC) {
                        if (sb[j] == 1) { m1 = ((p + j) << 12) | eb[j]; foundC = true; }
                        else if (sb[j] >= 0x80) pend |= 1ULL << (sb[j] & 63);
                    }
                }
                p += 8;
            }
            // in-register ballot fixpoint (deps point to lower lanes)
            unsigned long long C = 0ULL, A = 0ULL;
            bool res = false, isC = false;
            int ab = v;
            for (int r = 0; r < 70; ++r) {
                if (!res) {
                    unsigned long long live = pend & ~A;
                    if (live == 0ULL) {
                        res = true;
                        if (!foundC) { isC = true; ab = v; }
                        else { isC = false; ab = m1 & 0xFFF; }
                    } else {
                        int f = __ffsll((long long)live) - 1;
                        if ((C >> f) & 1ULL) {
                            res = true; isC = false; ab = (int)r2n[(c << 6) | f];
                        }
                    }
                }
                C = __ballot(res && isC);
                A = __ballot(res && !isC);
                if (__ballot(!res) == 0ULL) break;
            }
            stat[v] = isC ? 1 : 2;
            map_g[v] = ab;
            if (c < 63) stat[r2n[((c + 1) << 6) | lane]] = (unsigned char)(0x80 | lane);
        }
    }
    __syncthreads();

    // ---- relabel prefix + perm + globals ----
    int remb[4], cnt4 = 0;
    #pragma unroll
    for (int t = 0; t < 4; ++t) {
        int v = (tid << 2) | t;
        remb[t] = (stat[v] == 1) && !(lenb[v] & 0x80);
        cnt4 += remb[t];
    }
    int inc2 = cnt4;
    for (int off = 1; off < 64; off <<= 1) {
        int v = __shfl_up(inc2, off);
        if (lane >= off) inc2 += v;
    }
    if (lane == 63) wt[wv] = inc2;
    __syncthreads();
    if (wv == 0 && lane < 16) {
        int v = wt[lane];
        for (int off = 1; off < 16; off <<= 1) {
            int u2 = __shfl_up(v, off);
            if (lane >= off) v += u2;
        }
        wt[lane] = v;
    }
    __syncthreads();
    int woff2 = (wv > 0) ? wt[wv - 1] : 0;
    int run = woff2 + inc2 - cnt4;
    #pragma unroll
    for (int t = 0; t < 4; ++t) {
        int v = (tid << 2) | t;
        relab_g[v] = run;
        if (remb[t]) { perm_a[run] = v; ++run; }
        rem_g[v] = remb[t];
    }
    if (tid == 1023) nkeep_g[0] = run;
}

// ---------------- K56: all outputs; x region is pure atomic-add over zeroed base ----
__global__ void k56_outputs(const float* __restrict__ x, const int* __restrict__ map_g,
                            const int* __restrict__ rem_g, const int* __restrict__ relab_g,
                            const int* __restrict__ perm_a, const int* __restrict__ ei,
                            const int* __restrict__ batch, const int* __restrict__ nkeep_g,
                            float* __restrict__ out) {
    int idx = blockIdx.x * blockDim.x + threadIdx.x;
    if (idx < NN * ND) {
        int n = idx >> 6, d = idx & 63;
        int m = map_g[n];
        if (rem_g[m]) atomicAdd(&out[relab_g[m] * ND + d], x[idx]);
    } else if (idx < NN * ND + 2 * NE) {
        int e = idx - NN * ND;
        int row = e >> 16;
        int ee = e & (NE - 1);
        int s = ei[ee], t = ei[NE + ee];
        bool valid = (rem_g[s] != 0) && (rem_g[t] != 0);
        int endp = (row == 0) ? s : t;
        out[idx] = valid ? (float)relab_g[endp] : -1.0f;
    } else if (idx < NN * ND + 2 * NE + NN) {
        int r = idx - (NN * ND + 2 * NE);
        int nk = nkeep_g[0];
        out[idx] = (r < nk) ? (float)batch[perm_a[r]] : -1.0f;
    } else if (idx < NN * ND + 2 * NE + 2 * NN) {
        int r = idx - (NN * ND + 2 * NE + NN);
        int nk = nkeep_g[0];
        out[idx] = (r < nk) ? (float)perm_a[r] : -1.0f;
    }
}

extern "C" void kernel_launch(void* const* d_in, const int* in_sizes, int n_in,
                              void* d_out, int out_size, void* d_ws, size_t ws_size,
                              hipStream_t stream) {
    const float* x     = (const float*)d_in[0];
    const int*   ei    = (const int*)d_in[1];
    const int*   batch = (const int*)d_in[2];
    const float* wrel  = (const float*)d_in[3];
    const float* wroot = (const float*)d_in[4];
    const float* b     = (const float*)d_in[5];

    char* ws = (char*)d_ws;
    double* srel   = (double*)(ws + 0);
    double* sroot  = (double*)(ws + 32768);
    int*    map_g  = (int*)(ws + 65536);
    int*    rem_g  = (int*)(ws + 81920);
    int*    relab  = (int*)(ws + 98304);
    int*    rankp  = (int*)(ws + 114688);    // rank (K5) then perm (K34)
    int*    nkeep  = (int*)(ws + 131072);
    int*    cnt    = (int*)(ws + 131136);    // -> rl after K5
    int*    rowst  = (int*)(ws + 147520);
    int*    cursor = (int*)(ws + 163968);    // -> key after K4
    unsigned short* incsr = (unsigned short*)(ws + 180352);
    int*      rl  = cnt;
    unsigned* key = (unsigned*)cursor;

    float* out = (float*)d_out;

    hipMemsetAsync(cnt, 0, NN * sizeof(int), stream);
    k1_dots_count<<<NN * ND / 256, 256, 0, stream>>>(x, wrel, wroot, ei, srel, sroot, cnt);
    k2_scan<<<1, 1024, 0, stream>>>(cnt, rowst, cursor);
    k3_scatter<<<(NE / 4) / 256, 256, 0, stream>>>(ei, cursor, incsr);
    k4_keys<<<NN / 256, 256, 0, stream>>>(srel, sroot, b, rowst, incsr, key);
    k5_filtersort<<<(NN * 64) / 256, 256, 0, stream>>>(rowst, key, incsr, rl, rankp, out);
    k34_fix<<<1, 1024, 0, stream>>>(rowst, rl, incsr, rankp, map_g, rem_g, relab,
                                    rankp, nkeep);
    int total_out = NN * ND + 2 * NE + 2 * NN;  // 401408
    k56_outputs<<<(total_out + 255) / 256, 256, 0, stream>>>(x, map_g, rem_g, relab,
                                                             rankp, ei, batch, nkeep, out);
}

// Round 10
// 202.529 us; speedup vs baseline: 1.9292x; 1.1188x over previous
//
#include <hip/hip_runtime.h>

#define NN 4096
#define NE 65536
#define ND 64

// ---------- workspace layout (bytes) ----------
// 0      : srel   f64[NN]
// 32768  : sroot  f64[NN]
// 65536  : map    i32[NN]
// 81920  : rem    i32[NN]
// 98304  : relab  i32[NN]
// 114688 : rank   i32[NN]  (K5 writes; K34 stages, then overwrites with perm)
// 131072 : nkeep  i32
// 131136 : cnt    i32[NN]  (K1) -> rl (len|self<<16) i32[NN] (K5+)
// 147520 : rowst  i32[NN+1]
// 163968 : cursor i32[NN]  (K3) -> key u32[NN] (K4+)
// 180352 : incsr  u16[NE]  (128K; K3 scatter, K5 sorts rows in place)

// ---------------- K1: per-node dots + in-degree count (multi-CU) ----------------
// r5 lesson: no done-counter+__threadfence fusion (device fences from 1024 blocks
// forced ~2.1MB L2 writebacks, +60us).
__global__ void k1_dots_count(const float* __restrict__ x, const float* __restrict__ wrel,
                              const float* __restrict__ wroot, const int* __restrict__ ei,
                              double* __restrict__ srel, double* __restrict__ sroot,
                              int* __restrict__ cnt) {
    int gt = blockIdx.x * blockDim.x + threadIdx.x;
    int node = gt >> 6, lane = gt & 63;
    double xv = (double)x[gt];
    double pr = xv * (double)wrel[lane];
    double po = xv * (double)wroot[lane];
    for (int off = 32; off > 0; off >>= 1) {
        pr += __shfl_down(pr, off);
        po += __shfl_down(po, off);
    }
    if (lane == 0) {
        srel[node] = pr;
        sroot[node] = po;
    }
    if (gt < NE / 4) {
        const int4* eid4 = (const int4*)(ei + NE);
        int4 q = eid4[gt];
        atomicAdd(&cnt[q.x], 1);
        atomicAdd(&cnt[q.y], 1);
        atomicAdd(&cnt[q.z], 1);
        atomicAdd(&cnt[q.w], 1);
    }
}

// ---------------- K2: exclusive prefix scan of degrees (1 block) ----------------
__global__ void __launch_bounds__(1024) k2_scan(const int* __restrict__ cnt,
                                                int* __restrict__ rowst,
                                                int* __restrict__ cursor) {
    __shared__ int wt[16];
    int tid = threadIdx.x, lane = tid & 63, wv = tid >> 6;
    int4 c = ((const int4*)cnt)[tid];
    int tot = c.x + c.y + c.z + c.w;
    int inc = tot;
    for (int off = 1; off < 64; off <<= 1) {
        int v = __shfl_up(inc, off);
        if (lane >= off) inc += v;
    }
    if (lane == 63) wt[wv] = inc;
    __syncthreads();
    if (wv == 0 && lane < 16) {
        int v = wt[lane];
        for (int off = 1; off < 16; off <<= 1) {
            int u2 = __shfl_up(v, off);
            if (lane >= off) v += u2;
        }
        wt[lane] = v;
    }
    __syncthreads();
    int waveoff = (wv > 0) ? wt[wv - 1] : 0;
    int excl = waveoff + inc - tot;
    int4 rs;
    rs.x = excl; rs.y = excl + c.x; rs.z = excl + c.x + c.y; rs.w = excl + c.x + c.y + c.z;
    ((int4*)rowst)[tid] = rs;
    ((int4*)cursor)[tid] = rs;
    if (tid == 0) rowst[NN] = NE;
}

// ---------------- K3: scatter in-edges (row = dst, entry = src) ----------------
__global__ void k3_scatter(const int* __restrict__ ei, int* __restrict__ cursor,
                           unsigned short* __restrict__ incsr) {
    int i = blockIdx.x * blockDim.x + threadIdx.x;
    const int4* eis4 = (const int4*)ei;
    const int4* eid4 = (const int4*)(ei + NE);
    int4 s = eis4[i];
    int4 d = eid4[i];
    incsr[atomicAdd(&cursor[d.x], 1)] = (unsigned short)s.x;
    incsr[atomicAdd(&cursor[d.y], 1)] = (unsigned short)s.y;
    incsr[atomicAdd(&cursor[d.z], 1)] = (unsigned short)s.z;
    incsr[atomicAdd(&cursor[d.w], 1)] = (unsigned short)s.w;
}

// ---------------- K4: per-node agg + monotone key (multi-CU) ----------------
__global__ void k4_keys(const double* __restrict__ srel, const double* __restrict__ sroot,
                        const float* __restrict__ bptr, const int* __restrict__ rowst,
                        const unsigned short* __restrict__ incsr, unsigned* __restrict__ key) {
    int v = blockIdx.x * blockDim.x + threadIdx.x;
    int rs = rowst[v], re = rowst[v + 1];
    double s = 0.0;
    for (int e = rs; e < re; ++e) s += srel[(int)incsr[e]];
    double arg = s + sroot[v] + (double)bptr[0];
    float sc = tanhf((float)arg);                      // f32 saturation => ref ties
    unsigned m = __float_as_uint(sc);
    m = (m & 0x80000000u) ? ~m : (m | 0x80000000u);    // monotone ascending in score
    key[v] = m;
}

// ------- K5: per-row filter + 64-lane bitonic sort; side jobs: out-zero + rank -------
__global__ void k5_filtersort(const int* __restrict__ rowst, const unsigned* __restrict__ key,
                              unsigned short* __restrict__ incsr, int* __restrict__ rl,
                              int* __restrict__ rank_g, float* __restrict__ out) {
    // side job A: zero x_pooled region of out (replaces a memset dispatch)
    int g = blockIdx.x * blockDim.x + threadIdx.x;
    if (g < (NN * ND) / 4) ((float4*)out)[g] = make_float4(0.f, 0.f, 0.f, 0.f);

    int v = g >> 6, l = g & 63;
    int rs = rowst[v], deg = rowst[v + 1] - rs;
    unsigned mv = key[v];
    if (deg <= 64) {
        int u = (l < deg) ? (int)incsr[rs + l] : -1;
        bool isself = (l < deg) && (u == v);
        unsigned mu = (l < deg && !isself) ? key[u] : 0u;
        bool keep = (l < deg) && !isself && (mu > mv || (mu == mv && u < v));
        unsigned long long val = keep
            ? ((((unsigned long long)(~mu)) << 12) | (unsigned)u) : ~0ULL;
        int m = __popcll(__ballot(keep));
        bool selfAny = __ballot(isself) != 0ULL;
        // bitonic ascending => row sorted earliest-first (rank ascending)
        for (int k = 2; k <= 64; k <<= 1) {
            for (int j = k >> 1; j > 0; j >>= 1) {
                unsigned long long o = __shfl_xor(val, j);
                bool takeMin = ((l & k) == 0) == ((l & j) == 0);
                unsigned long long mn = (o < val) ? o : val;
                unsigned long long mx = (o < val) ? val : o;
                val = takeMin ? mn : mx;
            }
        }
        if (l < m) incsr[rs + l] = (unsigned short)(val & 0xFFFULL);
        if (l == 0) rl[v] = m | (selfAny ? 0x10000 : 0);
    } else if (l == 0) {
        int w = rs;
        bool selfAny = false;
        for (int e = rs; e < rs + deg; ++e) {
            int u = (int)incsr[e];
            if (u == v) { selfAny = true; continue; }
            unsigned mu = key[u];
            if (!(mu > mv || (mu == mv && u < v))) continue;
            int j = w;
            while (j > rs) {
                int q = (int)incsr[j - 1];
                unsigned mq = key[q];
                if (mu > mq || (mu == mq && u < q)) { incsr[j] = (unsigned short)q; --j; }
                else break;
            }
            incsr[j] = (unsigned short)u; ++w;
        }
        rl[v] = (w - rs) | (selfAny ? 0x10000 : 0);
    }

    // side job B: rank[v] = #{u : key_u>key_v || (key_u==key_v && u<v)} (per-wave)
    {
        int cntk = 0;
        const uint4* k4p = (const uint4*)key;
        #pragma unroll 4
        for (int i = 0; i < 16; ++i) {
            uint4 kq = k4p[(l << 4) | i];
            int u0 = (l << 6) | (i << 2);
            cntk += (kq.x > mv || (kq.x == mv && (u0    ) < v));
            cntk += (kq.y > mv || (kq.y == mv && (u0 + 1) < v));
            cntk += (kq.z > mv || (kq.z == mv && (u0 + 2) < v));
            cntk += (kq.w > mv || (kq.w == mv && (u0 + 3) < v));
        }
        for (int off = 32; off > 0; off >>= 1) cntk += __shfl_down(cntk, off);
        if (l == 0) rank_g[v] = cntk;
    }
}

// ---- K34: rank-chunk contraction, wave-0, UNCONDITIONAL batched LDS reads ----
// r9 lesson: per-element predicated reads serialize into 32 x ~130cy waits per
// chunk (128us). Fix: read all 16 entries & stats unconditionally (clamp &4095
// keeps stat[] in-bounds on over-read), mask AFTER in registers. Metadata is
// rank-indexed (depth-1 chain); resolve loop is pure register/ballot; in-chunk
// absorber node id via __shfl after the loop. Semantics == verified front-chase.
__global__ void __launch_bounds__(1024) k34_fix(
        const int* __restrict__ rowst, const int* __restrict__ rl,
        const unsigned short* __restrict__ incsr_g, const int* __restrict__ rank_g,
        int* __restrict__ map_g, int* __restrict__ rem_g, int* __restrict__ relab_g,
        int* __restrict__ perm_a, int* __restrict__ nkeep_g) {
    __shared__ __align__(16) char buf[159808];
    unsigned short* incsr = (unsigned short*)buf;              // 128K
    unsigned short* r2n   = (unsigned short*)(buf + 131072);   // 8K  rank -> node
    unsigned short* rlo   = (unsigned short*)(buf + 139264);   // 8K  rank -> row start
    unsigned char*  rLn   = (unsigned char*)(buf + 147456);    // 4K  rank -> filtered len
    unsigned char*  sf    = (unsigned char*)(buf + 151552);    // 4K  node -> self flag
    unsigned char*  stat  = (unsigned char*)(buf + 155648);    // 4K  node -> status
    int* wt = (int*)(buf + 159744);
    int tid = threadIdx.x, lane = tid & 63, wv = tid >> 6;

    // ---- stage (all 1024 threads) ----
    for (int i = tid; i < 8192; i += 1024)
        ((int4*)incsr)[i] = ((const int4*)incsr_g)[i];
    #pragma unroll
    for (int t = 0; t < 4; ++t) {
        int v = (tid << 2) | t;
        int rk = rank_g[v];
        int q  = rl[v];
        r2n[rk] = (unsigned short)v;
        rlo[rk] = (unsigned short)rowst[v];
        rLn[rk] = (unsigned char)(q & 0x7F);
        sf[v]   = (q & 0x10000) ? 1 : 0;
        stat[v] = 0;
    }
    __syncthreads();
    if (tid < 64) stat[r2n[tid]] = (unsigned char)(0x80 | tid);   // mark chunk 0
    __syncthreads();

    if (wv == 0) {
        for (int c = 0; c < 64; ++c) {
            int rk = (c << 6) | lane;
            int v  = (int)r2n[rk];
            int lo = (int)rlo[rk];
            int L  = (int)rLn[rk];
            int nv = (c < 63) ? (int)r2n[rk + 64] : 0;   // prefetch next-chunk node
            // phase A: 16 unconditional entry reads, then 16 unconditional stats
            int e[16];
            #pragma unroll
            for (int i = 0; i < 16; ++i) e[i] = (int)incsr[lo + i] & 4095;
            int s[16];
            #pragma unroll
            for (int i = 0; i < 16; ++i) s[i] = (int)stat[e[i]];
            int Lc = (L < 16) ? L : 16;
            unsigned cmask = 0;
            #pragma unroll
            for (int i = 0; i < 16; ++i)
                cmask |= (unsigned)((i < Lc) & (s[i] == 1)) << i;
            int m1pos = cmask ? (__ffs(cmask) - 1) : 9999;
            bool foundC = (cmask != 0);
            int m1node = v;
            #pragma unroll
            for (int i = 0; i < 16; ++i) if (i == m1pos) m1node = e[i];
            unsigned long long pend = 0ULL;
            #pragma unroll
            for (int i = 0; i < 16; ++i)
                if (i < Lc && i < m1pos && s[i] >= 0x80) pend |= 1ULL << (s[i] & 63);
            // phase B: rare rows longer than 16 (same batched pattern)
            int p = 16;
            while (__any(p < L && !foundC)) {
                if (p < L && !foundC) {
                    int eb[16], sb[16];
                    #pragma unroll
                    for (int j = 0; j < 16; ++j) eb[j] = (int)incsr[lo + p + j] & 4095;
                    #pragma unroll
                    for (int j = 0; j < 16; ++j) sb[j] = (int)stat[eb[j]];
                    int Lb = L - p; if (Lb > 16) Lb = 16;
                    unsigned cb = 0;
                    #pragma unroll
                    for (int j = 0; j < 16; ++j)
                        cb |= (unsigned)((j < Lb) & (sb[j] == 1)) << j;
                    int mb = cb ? (__ffs(cb) - 1) : 9999;
                    #pragma unroll
                    for (int j = 0; j < 16; ++j) if (j == mb) m1node = eb[j];
                    foundC = foundC || (cb != 0);
                    #pragma unroll
                    for (int j = 0; j < 16; ++j)
                        if (j < Lb && j < mb && sb[j] >= 0x80) pend |= 1ULL << (sb[j] & 63);
                }
                p += 16;
            }
            // in-register ballot resolve (deps point to lower lanes)
            unsigned long long C = 0ULL, A = 0ULL;
            bool res = false, isC = false;
            int ab = v, fsel = -1;
            for (int r = 0; r < 66; ++r) {
                if (!res) {
                    unsigned long long live = pend & ~A;
                    if (live == 0ULL) {
                        res = true;
                        if (!foundC) isC = true;
                        else { isC = false; ab = m1node; }
                    } else {
                        int f = __ffsll((long long)live) - 1;
                        if ((C >> f) & 1ULL) { res = true; isC = false; fsel = f; }
                    }
                }
                C = __ballot(res && isC);
                A = __ballot(res && !isC);
                if (__ballot(!res) == 0ULL) break;
            }
            {
                int abf = __shfl(v, (fsel < 0) ? 0 : fsel);   // node id of lane fsel
                if (fsel >= 0) ab = abf;
            }
            stat[v] = isC ? 1 : 2;
            map_g[v] = ab;
            if (c < 63) stat[nv] = (unsigned char)(0x80 | lane);   // mark next chunk
        }
    }
    __syncthreads();

    // ---- relabel prefix + perm + globals ----
    int remb[4], cnt4 = 0;
    #pragma unroll
    for (int t = 0; t < 4; ++t) {
        int v = (tid << 2) | t;
        remb[t] = (stat[v] == 1) && !sf[v];
        cnt4 += remb[t];
    }
    int inc2 = cnt4;
    for (int off = 1; off < 64; off <<= 1) {
        int v = __shfl_up(inc2, off);
        if (lane >= off) inc2 += v;
    }
    if (lane == 63) wt[wv] = inc2;
    __syncthreads();
    if (wv == 0 && lane < 16) {
        int v = wt[lane];
        for (int off = 1; off < 16; off <<= 1) {
            int u2 = __shfl_up(v, off);
            if (lane >= off) v += u2;
        }
        wt[lane] = v;
    }
    __syncthreads();
    int woff2 = (wv > 0) ? wt[wv - 1] : 0;
    int run = woff2 + inc2 - cnt4;
    #pragma unroll
    for (int t = 0; t < 4; ++t) {
        int v = (tid << 2) | t;
        relab_g[v] = run;
        if (remb[t]) { perm_a[run] = v; ++run; }
        rem_g[v] = remb[t];
    }
    if (tid == 1023) nkeep_g[0] = run;
}

// ---------------- K56: all outputs; x region is pure atomic-add over zeroed base ----
__global__ void k56_outputs(const float* __restrict__ x, const int* __restrict__ map_g,
                            const int* __restrict__ rem_g, const int* __restrict__ relab_g,
                            const int* __restrict__ perm_a, const int* __restrict__ ei,
                            const int* __restrict__ batch, const int* __restrict__ nkeep_g,
                            float* __restrict__ out) {
    int idx = blockIdx.x * blockDim.x + threadIdx.x;
    if (idx < NN * ND) {
        int n = idx >> 6, d = idx & 63;
        int m = map_g[n];
        if (rem_g[m]) atomicAdd(&out[relab_g[m] * ND + d], x[idx]);
    } else if (idx < NN * ND + 2 * NE) {
        int e = idx - NN * ND;
        int row = e >> 16;
        int ee = e & (NE - 1);
        int s = ei[ee], t = ei[NE + ee];
        bool valid = (rem_g[s] != 0) && (rem_g[t] != 0);
        int endp = (row == 0) ? s : t;
        out[idx] = valid ? (float)relab_g[endp] : -1.0f;
    } else if (idx < NN * ND + 2 * NE + NN) {
        int r = idx - (NN * ND + 2 * NE);
        int nk = nkeep_g[0];
        out[idx] = (r < nk) ? (float)batch[perm_a[r]] : -1.0f;
    } else if (idx < NN * ND + 2 * NE + 2 * NN) {
        int r = idx - (NN * ND + 2 * NE + NN);
        int nk = nkeep_g[0];
        out[idx] = (r < nk) ? (float)perm_a[r] : -1.0f;
    }
}

extern "C" void kernel_launch(void* const* d_in, const int* in_sizes, int n_in,
                              void* d_out, int out_size, void* d_ws, size_t ws_size,
                              hipStream_t stream) {
    const float* x     = (const float*)d_in[0];
    const int*   ei    = (const int*)d_in[1];
    const int*   batch = (const int*)d_in[2];
    const float* wrel  = (const float*)d_in[3];
    const float* wroot = (const float*)d_in[4];
    const float* b     = (const float*)d_in[5];

    char* ws = (char*)d_ws;
    double* srel   = (double*)(ws + 0);
    double* sroot  = (double*)(ws + 32768);
    int*    map_g  = (int*)(ws + 65536);
    int*    rem_g  = (int*)(ws + 81920);
    int*    relab  = (int*)(ws + 98304);
    int*    rankp  = (int*)(ws + 114688);    // rank (K5) then perm (K34)
    int*    nkeep  = (int*)(ws + 131072);
    int*    cnt    = (int*)(ws + 131136);    // -> rl after K5
    int*    rowst  = (int*)(ws + 147520);
    int*    cursor = (int*)(ws + 163968);    // -> key after K4
    unsigned short* incsr = (unsigned short*)(ws + 180352);
    int*      rl  = cnt;
    unsigned* key = (unsigned*)cursor;

    float* out = (float*)d_out;

    hipMemsetAsync(cnt, 0, NN * sizeof(int), stream);
    k1_dots_count<<<NN * ND / 256, 256, 0, stream>>>(x, wrel, wroot, ei, srel, sroot, cnt);
    k2_scan<<<1, 1024, 0, stream>>>(cnt, rowst, cursor);
    k3_scatter<<<(NE / 4) / 256, 256, 0, stream>>>(ei, cursor, incsr);
    k4_keys<<<NN / 256, 256, 0, stream>>>(srel, sroot, b, rowst, incsr, key);
    k5_filtersort<<<(NN * 64) / 256, 256, 0, stream>>>(rowst, key, incsr, rl, rankp, out);
    k34_fix<<<1, 1024, 0, stream>>>(rowst, rl, incsr, rankp, map_g, rem_g, relab,
                                    rankp, nkeep);
    int total_out = NN * ND + 2 * NE + 2 * NN;  // 401408
    k56_outputs<<<(total_out + 255) / 256, 256, 0, stream>>>(x, map_g, rem_g, relab,
                                                             rankp, ei, batch, nkeep, out);
}

// Round 11
// 139.737 us; speedup vs baseline: 2.7962x; 1.4494x over previous
//
#include <hip/hip_runtime.h>

#define NN 4096
#define NE 65536
#define ND 64

// ---------- workspace layout (bytes) ----------
// 0      : srel   f64[NN]
// 32768  : sroot  f64[NN]
// 65536  : map    i32[NN]
// 81920  : rem    i32[NN]
// 98304  : relab  i32[NN]
// 114688 : perma  i32[NN]
// 131072 : nkeep  i32
// 131136 : cnt    i32[NN]  (K1) -> rl (len|self<<16) i32[NN] (K5+)
// 147520 : rowst  i32[NN+1]
// 163968 : cursor i32[NN]  (K3) -> key u32[NN] (K4+)
// 180352 : incsr  u16[NE]  (128K; K3 scatter, K5 sorts rows in place)

// ---------------- K1: per-node dots + in-degree count (multi-CU) ----------------
// r5 lesson: no done-counter+__threadfence fusion (device fences from 1024 blocks
// forced ~2.1MB L2 writebacks, +60us).
__global__ void k1_dots_count(const float* __restrict__ x, const float* __restrict__ wrel,
                              const float* __restrict__ wroot, const int* __restrict__ ei,
                              double* __restrict__ srel, double* __restrict__ sroot,
                              int* __restrict__ cnt) {
    int gt = blockIdx.x * blockDim.x + threadIdx.x;
    int node = gt >> 6, lane = gt & 63;
    double xv = (double)x[gt];
    double pr = xv * (double)wrel[lane];
    double po = xv * (double)wroot[lane];
    for (int off = 32; off > 0; off >>= 1) {
        pr += __shfl_down(pr, off);
        po += __shfl_down(po, off);
    }
    if (lane == 0) {
        srel[node] = pr;
        sroot[node] = po;
    }
    if (gt < NE / 4) {
        const int4* eid4 = (const int4*)(ei + NE);
        int4 q = eid4[gt];
        atomicAdd(&cnt[q.x], 1);
        atomicAdd(&cnt[q.y], 1);
        atomicAdd(&cnt[q.z], 1);
        atomicAdd(&cnt[q.w], 1);
    }
}

// ---------------- K2: exclusive prefix scan of degrees (1 block) ----------------
__global__ void __launch_bounds__(1024) k2_scan(const int* __restrict__ cnt,
                                                int* __restrict__ rowst,
                                                int* __restrict__ cursor) {
    __shared__ int wt[16];
    int tid = threadIdx.x, lane = tid & 63, wv = tid >> 6;
    int4 c = ((const int4*)cnt)[tid];
    int tot = c.x + c.y + c.z + c.w;
    int inc = tot;
    for (int off = 1; off < 64; off <<= 1) {
        int v = __shfl_up(inc, off);
        if (lane >= off) inc += v;
    }
    if (lane == 63) wt[wv] = inc;
    __syncthreads();
    if (wv == 0 && lane < 16) {
        int v = wt[lane];
        for (int off = 1; off < 16; off <<= 1) {
            int u2 = __shfl_up(v, off);
            if (lane >= off) v += u2;
        }
        wt[lane] = v;
    }
    __syncthreads();
    int waveoff = (wv > 0) ? wt[wv - 1] : 0;
    int excl = waveoff + inc - tot;
    int4 rs;
    rs.x = excl; rs.y = excl + c.x; rs.z = excl + c.x + c.y; rs.w = excl + c.x + c.y + c.z;
    ((int4*)rowst)[tid] = rs;
    ((int4*)cursor)[tid] = rs;
    if (tid == 0) rowst[NN] = NE;
}

// ---------------- K3: scatter in-edges (row = dst, entry = src) ----------------
__global__ void k3_scatter(const int* __restrict__ ei, int* __restrict__ cursor,
                           unsigned short* __restrict__ incsr) {
    int i = blockIdx.x * blockDim.x + threadIdx.x;
    const int4* eis4 = (const int4*)ei;
    const int4* eid4 = (const int4*)(ei + NE);
    int4 s = eis4[i];
    int4 d = eid4[i];
    incsr[atomicAdd(&cursor[d.x], 1)] = (unsigned short)s.x;
    incsr[atomicAdd(&cursor[d.y], 1)] = (unsigned short)s.y;
    incsr[atomicAdd(&cursor[d.z], 1)] = (unsigned short)s.z;
    incsr[atomicAdd(&cursor[d.w], 1)] = (unsigned short)s.w;
}

// ---------------- K4: per-node agg + monotone key (multi-CU) ----------------
__global__ void k4_keys(const double* __restrict__ srel, const double* __restrict__ sroot,
                        const float* __restrict__ bptr, const int* __restrict__ rowst,
                        const unsigned short* __restrict__ incsr, unsigned* __restrict__ key) {
    int v = blockIdx.x * blockDim.x + threadIdx.x;
    int rs = rowst[v], re = rowst[v + 1];
    double s = 0.0;
    for (int e = rs; e < re; ++e) s += srel[(int)incsr[e]];
    double arg = s + sroot[v] + (double)bptr[0];
    float sc = tanhf((float)arg);                      // f32 saturation => ref ties
    unsigned m = __float_as_uint(sc);
    m = (m & 0x80000000u) ? ~m : (m | 0x80000000u);    // monotone ascending in score
    key[v] = m;
}

// ------- K5: per-row filter + 64-lane bitonic sort; side job: out-zero -------
__global__ void k5_filtersort(const int* __restrict__ rowst, const unsigned* __restrict__ key,
                              unsigned short* __restrict__ incsr, int* __restrict__ rl,
                              float* __restrict__ out) {
    // side job: zero x_pooled region of out (replaces a memset dispatch; proven r7-r10)
    int g = blockIdx.x * blockDim.x + threadIdx.x;
    if (g < (NN * ND) / 4) ((float4*)out)[g] = make_float4(0.f, 0.f, 0.f, 0.f);

    int v = g >> 6, l = g & 63;
    int rs = rowst[v], deg = rowst[v + 1] - rs;
    unsigned mv = key[v];
    if (deg <= 64) {
        int u = (l < deg) ? (int)incsr[rs + l] : -1;
        bool isself = (l < deg) && (u == v);
        unsigned mu = (l < deg && !isself) ? key[u] : 0u;
        bool keep = (l < deg) && !isself && (mu > mv || (mu == mv && u < v));
        unsigned long long val = keep
            ? ((((unsigned long long)(~mu)) << 12) | (unsigned)u) : ~0ULL;
        int m = __popcll(__ballot(keep));
        bool selfAny = __ballot(isself) != 0ULL;
        // bitonic ascending => row sorted earliest-first
        for (int k = 2; k <= 64; k <<= 1) {
            for (int j = k >> 1; j > 0; j >>= 1) {
                unsigned long long o = __shfl_xor(val, j);
                bool takeMin = ((l & k) == 0) == ((l & j) == 0);
                unsigned long long mn = (o < val) ? o : val;
                unsigned long long mx = (o < val) ? val : o;
                val = takeMin ? mn : mx;
            }
        }
        if (l < m) incsr[rs + l] = (unsigned short)(val & 0xFFFULL);
        if (l == 0) rl[v] = m | (selfAny ? 0x10000 : 0);
    } else if (l == 0) {
        // fallback (not expected for this input): sequential filter + insertion
        int w = rs;
        bool selfAny = false;
        for (int e = rs; e < rs + deg; ++e) {
            int u = (int)incsr[e];
            if (u == v) { selfAny = true; continue; }
            unsigned mu = key[u];
            if (!(mu > mv || (mu == mv && u < v))) continue;
            int j = w;
            while (j > rs) {
                int q = (int)incsr[j - 1];
                unsigned mq = key[q];
                if (mu > mq || (mu == mq && u < q)) { incsr[j] = (unsigned short)q; --j; }
                else break;
            }
            incsr[j] = (unsigned short)u; ++w;
        }
        rl[v] = (w - rs) | (selfAny ? 0x10000 : 0);
    }
}

// ---- K34: 1-CU spin front-chase fixpoint on pre-sorted rows (r4, 47us proven) ----
// 16 waves, 4 nodes/thread. Sorted rows: front = min live key; front center =>
// absorb (== verified mC<minU rule); absorbed fronts skipped exactly once;
// exhausted => center. Polls are 1 u8 LDS read; hot nodes broadcast.
// r7/r9/r10 lesson: rank-chunk single-wave variants are latency-naked (103-186us);
// the multi-wave spin hides the same LDS latencies behind 64 waves of TLP.
__global__ void __launch_bounds__(1024) k34_fix(
        const int* __restrict__ rowst, const int* __restrict__ rl,
        const unsigned short* __restrict__ incsr_g,
        int* __restrict__ map_g, int* __restrict__ rem_g, int* __restrict__ relab_g,
        int* __restrict__ perm_a, int* __restrict__ nkeep_g) {
    __shared__ __align__(16) char buf[135232];
    unsigned short* incsr = (unsigned short*)buf;                        // 128K
    volatile unsigned char* stat = (volatile unsigned char*)(buf + 131072);  // 4K
    int* wt = (int*)(buf + 135168);
    int tid = threadIdx.x, lane = tid & 63, wv = tid >> 6;

    for (int i = tid; i < 131072 / 16; i += 1024)
        ((int4*)incsr)[i] = ((const int4*)incsr_g)[i];
    ((int*)(buf + 131072))[tid] = 0;
    int4 rsq = ((const int4*)rowst)[tid];
    int4 rlq = ((const int4*)rl)[tid];
    int rs4[4] = {rsq.x, rsq.y, rsq.z, rsq.w};
    int rq4[4] = {rlq.x, rlq.y, rlq.z, rlq.w};
    __syncthreads();

    unsigned resolved = 0, centerm = 0, selfm = 0;
    int pos4[4], re4[4], fu4[4] = {0, 0, 0, 0};
    #pragma unroll
    for (int t = 0; t < 4; ++t) {
        int v = 4 * tid + t;
        int m = rq4[t] & 0xFFFF;
        if (rq4[t] & 0x10000) selfm |= 1u << t;
        int lo = rs4[t];
        pos4[t] = lo; re4[t] = lo + m;
        if (m == 0) {                                    // no earlier in-nbrs: center
            map_g[v] = v; stat[v] = 1;
            centerm |= 1u << t; resolved |= 1u << t;
        } else {
            fu4[t] = (int)incsr[lo];
        }
    }

    int guard = 0;
    while (resolved != 0xFu && guard < 1000000) {
        ++guard;
        bool prog = false;
        #pragma unroll
        for (int t = 0; t < 4; ++t) {
            if (resolved & (1u << t)) continue;
            int v = 4 * tid + t;
            int u = fu4[t];
            int st = (int)stat[u];
            if (st == 0) continue;                       // front unresolved: blocked
            prog = true;
            if (st == 1) {                               // front is center: absorbed
                map_g[v] = u; stat[v] = 2; resolved |= 1u << t; continue;
            }
            int p = pos4[t] + 1, hi = re4[t];            // front absorbed: advance
            bool done = false;
            while (p < hi) {
                u = (int)incsr[p];
                st = (int)stat[u];
                if (st == 2) { ++p; continue; }
                if (st == 1) {
                    map_g[v] = u; stat[v] = 2; resolved |= 1u << t; done = true;
                }
                break;                                   // st==0: blocked here
            }
            if (!done) {
                if (p >= hi) {                           // all earlier absorbed: center
                    map_g[v] = v; stat[v] = 1; centerm |= 1u << t; resolved |= 1u << t;
                } else {
                    pos4[t] = p; fu4[t] = u;
                }
            }
        }
        if (__ballot(prog) == 0) __builtin_amdgcn_s_sleep(1);
    }
    __syncthreads();

    // relabel prefix + perm + globals
    int remb[4], cnt4 = 0;
    #pragma unroll
    for (int t = 0; t < 4; ++t) {
        remb[t] = ((centerm >> t) & 1) && !((selfm >> t) & 1);
        cnt4 += remb[t];
    }
    int inc2 = cnt4;
    for (int off = 1; off < 64; off <<= 1) {
        int v = __shfl_up(inc2, off);
        if (lane >= off) inc2 += v;
    }
    if (lane == 63) wt[wv] = inc2;
    __syncthreads();
    if (wv == 0 && lane < 16) {
        int v = wt[lane];
        for (int off = 1; off < 16; off <<= 1) {
            int u2 = __shfl_up(v, off);
            if (lane >= off) v += u2;
        }
        wt[lane] = v;
    }
    __syncthreads();
    int woff2 = (wv > 0) ? wt[wv - 1] : 0;
    int run = woff2 + inc2 - cnt4;
    #pragma unroll
    for (int t = 0; t < 4; ++t) {
        int v = 4 * tid + t;
        relab_g[v] = run;
        if (remb[t]) { perm_a[run] = v; ++run; }
        rem_g[v] = remb[t];
    }
    if (tid == 1023) nkeep_g[0] = run;
}

// ---------------- K56: all outputs; x region is pure atomic-add over zeroed base ----
__global__ void k56_outputs(const float* __restrict__ x, const int* __restrict__ map_g,
                            const int* __restrict__ rem_g, const int* __restrict__ relab_g,
                            const int* __restrict__ perm_a, const int* __restrict__ ei,
                            const int* __restrict__ batch, const int* __restrict__ nkeep_g,
                            float* __restrict__ out) {
    int idx = blockIdx.x * blockDim.x + threadIdx.x;
    if (idx < NN * ND) {
        int n = idx >> 6, d = idx & 63;
        int m = map_g[n];                 // m==n for centers & kept free nodes
        if (rem_g[m]) atomicAdd(&out[relab_g[m] * ND + d], x[idx]);
    } else if (idx < NN * ND + 2 * NE) {
        int e = idx - NN * ND;
        int row = e >> 16;                // NE == 1<<16
        int ee = e & (NE - 1);
        int s = ei[ee], t = ei[NE + ee];
        bool valid = (rem_g[s] != 0) && (rem_g[t] != 0);
        int endp = (row == 0) ? s : t;
        out[idx] = valid ? (float)relab_g[endp] : -1.0f;
    } else if (idx < NN * ND + 2 * NE + NN) {
        int r = idx - (NN * ND + 2 * NE);
        int nk = nkeep_g[0];
        out[idx] = (r < nk) ? (float)batch[perm_a[r]] : -1.0f;
    } else if (idx < NN * ND + 2 * NE + 2 * NN) {
        int r = idx - (NN * ND + 2 * NE + NN);
        int nk = nkeep_g[0];
        out[idx] = (r < nk) ? (float)perm_a[r] : -1.0f;
    }
}

extern "C" void kernel_launch(void* const* d_in, const int* in_sizes, int n_in,
                              void* d_out, int out_size, void* d_ws, size_t ws_size,
                              hipStream_t stream) {
    const float* x     = (const float*)d_in[0];
    const int*   ei    = (const int*)d_in[1];
    const int*   batch = (const int*)d_in[2];
    const float* wrel  = (const float*)d_in[3];
    const float* wroot = (const float*)d_in[4];
    const float* b     = (const float*)d_in[5];

    char* ws = (char*)d_ws;
    double* srel   = (double*)(ws + 0);
    double* sroot  = (double*)(ws + 32768);
    int*    map_g  = (int*)(ws + 65536);
    int*    rem_g  = (int*)(ws + 81920);
    int*    relab  = (int*)(ws + 98304);
    int*    perma  = (int*)(ws + 114688);
    int*    nkeep  = (int*)(ws + 131072);
    int*    cnt    = (int*)(ws + 131136);    // -> rl after K5
    int*    rowst  = (int*)(ws + 147520);
    int*    cursor = (int*)(ws + 163968);    // -> key after K4
    unsigned short* incsr = (unsigned short*)(ws + 180352);
    int*      rl  = cnt;
    unsigned* key = (unsigned*)cursor;

    float* out = (float*)d_out;

    hipMemsetAsync(cnt, 0, NN * sizeof(int), stream);
    k1_dots_count<<<NN * ND / 256, 256, 0, stream>>>(x, wrel, wroot, ei, srel, sroot, cnt);
    k2_scan<<<1, 1024, 0, stream>>>(cnt, rowst, cursor);
    k3_scatter<<<(NE / 4) / 256, 256, 0, stream>>>(ei, cursor, incsr);
    k4_keys<<<NN / 256, 256, 0, stream>>>(srel, sroot, b, rowst, incsr, key);
    k5_filtersort<<<(NN * 64) / 256, 256, 0, stream>>>(rowst, key, incsr, rl, out);
    k34_fix<<<1, 1024, 0, stream>>>(rowst, rl, incsr, map_g, rem_g, relab, perma, nkeep);
    int total_out = NN * ND + 2 * NE + 2 * NN;  // 401408
    k56_outputs<<<(total_out + 255) / 256, 256, 0, stream>>>(x, map_g, rem_g, relab,
                                                             perma, ei, batch, nkeep, out);
}